// Round 5
// baseline (419.400 us; speedup 1.0000x reference)
//
#include <hip/hip_runtime.h>
#include <hip/hip_bf16.h>

// Problem constants: B=4, H=W=256, C=64, OC=64, K=3, PAD=1
#define FEAT_N (4*64*256*256)
#define OFFS_N (4*18*256*256)
#define WTF_N  (576*64)            // deform weights, bf16, MFMA-B-fragment order
#define WT2F_N (576*32)            // offset-conv weights, bf16 frags, N padded to 32

typedef __attribute__((ext_vector_type(8))) short short8;
typedef __attribute__((ext_vector_type(4))) float float4v;
typedef __attribute__((ext_vector_type(4))) unsigned uint4v;

__device__ __forceinline__ unsigned short f2bf(float f) {
    union { float f; unsigned u; } c; c.f = f;
    unsigned r = c.u + 0x7FFF + ((c.u >> 16) & 1);   // RNE
    return (unsigned short)(r >> 16);
}

__device__ __forceinline__ unsigned pack_bf16x2(float lo, float hi) {
    float2 v; v.x = lo; v.y = hi;
    __hip_bfloat162 h = __float22bfloat162_rn(v);
    union { __hip_bfloat162 h; unsigned u; } c; c.h = h;
    return c.u;
}

__device__ __forceinline__ float bf_lo(unsigned u) { return __uint_as_float(u << 16); }
__device__ __forceinline__ float bf_hi(unsigned u) { return __uint_as_float(u & 0xFFFF0000u); }

// ---------------------------------------------------------------------------
// Weight prep (EXACT R4): deform weights -> wtf (B-frags, 4 N-tiles);
// offset-conv weights -> wt2f (B-frags, 2 N-tiles, oc>=18 zero).
// ---------------------------------------------------------------------------
__global__ __launch_bounds__(256) void prep_weights(const float* __restrict__ dw,
                                                    const float* __restrict__ ow,
                                                    unsigned short* __restrict__ wtf,
                                                    unsigned short* __restrict__ wt2f) {
    int idx = blockIdx.x * 256 + threadIdx.x;
    if (idx < WTF_N) {
        int j    = idx & 7;
        int lane = (idx >> 3) & 63;
        int nt   = (idx >> 9) & 3;
        int ks   = idx >> 11;
        int k    = ks * 32 + ((lane >> 4) << 3) + j;
        int tap  = k >> 6;
        int ic   = k & 63;
        int n    = nt * 16 + (lane & 15);
        wtf[idx] = f2bf(dw[n * 576 + ic * 9 + tap]);
    }
    int i2 = idx - WTF_N;
    if (i2 >= 0 && i2 < WT2F_N) {
        int j    = i2 & 7;
        int lane = (i2 >> 3) & 63;
        int nt   = (i2 >> 9) & 1;
        int ks   = i2 >> 10;
        int k    = ks * 32 + ((lane >> 4) << 3) + j;
        int tap  = k >> 6;
        int ic   = k & 63;
        int n    = nt * 16 + (lane & 15);
        wt2f[i2] = (n < 18) ? f2bf(ow[n * 576 + ic * 9 + tap]) : (unsigned short)0;
    }
}

// ---------------------------------------------------------------------------
// conv1 (EXACT R4, known-pass): x[4,3,256,256] * w + b -> featp, NHWC bf16:
// dword index for (b,y,x,cp) = ((b<<16)+(y<<8)+x)*32 + cp.
// ---------------------------------------------------------------------------
__global__ __launch_bounds__(256) void conv1_kernel(const float* __restrict__ x,
                                                    const float* __restrict__ cw,
                                                    const float* __restrict__ cb,
                                                    unsigned short* __restrict__ featp) {
    __shared__ __align__(16) float wl[64 * 28];
    __shared__ float bl[64];
    const int tid = threadIdx.x;
    for (int i = tid; i < 64 * 28; i += 256) {
        int oc = i / 28;
        int t  = i - oc * 28;
        wl[i] = (t < 27) ? cw[oc * 27 + t] : 0.f;
    }
    if (tid < 64) bl[tid] = cb[tid];
    __syncthreads();

    const int bx = blockIdx.x;
    const int b  = bx >> 8;
    const int h  = bx & 255;
    const int w  = tid;

    float xr[3][3][3];
#pragma unroll
    for (int ic = 0; ic < 3; ic++) {
#pragma unroll
        for (int r = 0; r < 3; r++) {
            int row = h - 1 + r;
            bool rok = (unsigned)row < 256u;
#pragma unroll
            for (int j = 0; j < 3; j++) {
                int col = w - 1 + j;
                bool ok = rok && ((unsigned)col < 256u);
                xr[ic][r][j] = ok ? x[((b * 3 + ic) << 16) + (row << 8) + col] : 0.f;
            }
        }
    }

    unsigned* dst = (unsigned*)featp + ((((size_t)b << 16) + (h << 8) + w) << 5);
    for (int g = 0; g < 8; g++) {               // dynamic: keep code compact
        uint4v v;
#pragma unroll
        for (int q = 0; q < 4; q++) {
            const int ocp = 4 * g + q;
            float a0 = bl[2 * ocp], a1 = bl[2 * ocp + 1];
            const float* wp0 = &wl[(2 * ocp) * 28];
            const float* wp1 = wp0 + 28;
#pragma unroll
            for (int ic = 0; ic < 3; ic++)
#pragma unroll
                for (int i = 0; i < 3; i++)
#pragma unroll
                    for (int j = 0; j < 3; j++) {
                        float xv = xr[ic][i][j];
                        a0 += xv * wp0[ic * 9 + i * 3 + j];
                        a1 += xv * wp1[ic * 9 + i * 3 + j];
                    }
            v[q] = pack_bf16x2(a0, a1);
        }
        *(uint4v*)(dst + 4 * g) = v;
    }
}

// ---------------------------------------------------------------------------
// conv2 (EXACT R4, known-pass): MFMA with 1-tap A-prefetch pipeline.
// ---------------------------------------------------------------------------
__global__ __launch_bounds__(256) void conv2_kernel(const unsigned short* __restrict__ featp,
                                                    const unsigned short* __restrict__ wt2f,
                                                    const float* __restrict__ ob,
                                                    float* __restrict__ offs) {
    const int tid  = threadIdx.x;
    const int lane = tid & 63;
    const int wave = tid >> 6;
    const int lm   = lane & 15;
    const int quad = lane >> 4;

    const int bx = blockIdx.x;
    const int strip = ((bx & 7) << 8) | (bx >> 3);
    const int wo_base = (strip & 1) << 7;
    const int ho = (strip >> 1) & 255;
    const int b  = strip >> 9;

    const unsigned* fpq = (const unsigned*)featp + ((size_t)b << 21) + quad * 4;
    const int colb = wo_base + wave * 32 + lm;

    float4v acc[2][2];
#pragma unroll
    for (int mt = 0; mt < 2; mt++)
#pragma unroll
        for (int nt = 0; nt < 2; nt++) acc[mt][nt] = (float4v)0.f;

    uint4v A[2][2];   // [mt][half]: current tap's A-frag data

#define C2LOAD(KY, KX, DST)                                                      \
    {                                                                            \
        const int row = ho - 1 + (KY);                                           \
        const bool rok = (unsigned)row < 256u;                                   \
        _Pragma("unroll")                                                        \
        for (int mt = 0; mt < 2; mt++) {                                         \
            const int col = colb + mt * 16 + (KX) - 1;                           \
            DST[mt][0] = (uint4v)0;                                              \
            DST[mt][1] = (uint4v)0;                                              \
            if (rok && (unsigned)col < 256u) {                                   \
                const unsigned* p = fpq + (((row << 8) + col) << 5);             \
                DST[mt][0] = *(const uint4v*)p;                                  \
                DST[mt][1] = *(const uint4v*)(p + 16);                           \
            }                                                                    \
        }                                                                        \
    }

    C2LOAD(0, 0, A);

#pragma unroll
    for (int tap = 0; tap < 9; tap++) {
        short8 bfr[2][2];
        const unsigned short* wp = wt2f + (size_t)(tap * 2) * 1024 + lane * 8;
#pragma unroll
        for (int st = 0; st < 2; st++) {
            bfr[st][0] = *(const short8*)(wp + st * 1024);
            bfr[st][1] = *(const short8*)(wp + st * 1024 + 512);
        }
        uint4v N[2][2];
        if (tap < 8) {
            const int tn  = tap + 1;
            const int tky = tn / 3;
            const int tkx = tn - 3 * tky;
            C2LOAD(tky, tkx, N);
        }
#pragma unroll
        for (int mt = 0; mt < 2; mt++) {
            union { short8 v; uint4v u; } f0, f1;
            f0.u = A[mt][0]; f1.u = A[mt][1];
            acc[mt][0] = __builtin_amdgcn_mfma_f32_16x16x32_bf16(f0.v, bfr[0][0], acc[mt][0], 0, 0, 0);
            acc[mt][1] = __builtin_amdgcn_mfma_f32_16x16x32_bf16(f0.v, bfr[0][1], acc[mt][1], 0, 0, 0);
            acc[mt][0] = __builtin_amdgcn_mfma_f32_16x16x32_bf16(f1.v, bfr[1][0], acc[mt][0], 0, 0, 0);
            acc[mt][1] = __builtin_amdgcn_mfma_f32_16x16x32_bf16(f1.v, bfr[1][1], acc[mt][1], 0, 0, 0);
        }
        if (tap < 8) {
#pragma unroll
            for (int mt = 0; mt < 2; mt++) {
                A[mt][0] = N[mt][0];
                A[mt][1] = N[mt][1];
            }
        }
    }
#undef C2LOAD

#pragma unroll
    for (int nt = 0; nt < 2; nt++) {
        int oc = nt * 16 + lm;
        if (oc < 18) {
            float bv = ob[oc];
            float* op = offs + (((size_t)(b * 18 + oc)) << 16) + (ho << 8)
                      + wo_base + wave * 32 + quad * 4;
#pragma unroll
            for (int mt = 0; mt < 2; mt++) {
                float4 v = {acc[mt][nt][0] + bv, acc[mt][nt][1] + bv,
                            acc[mt][nt][2] + bv, acc[mt][nt][3] + bv};
                *(float4*)(op + mt * 16) = v;
            }
        }
    }
}

// ---------------------------------------------------------------------------
// deform conv: operand-SWAPPED per-corner MFMA. Same block/strip/gather/
// coords/weights as the passing R4 kernel; the bilinear combine is replaced
// by: for each corner c, tmp = W·feat_c (MFMA, raw bf16 gathers as the B
// operand directly), then acc += w_c * tmp (lane-local: D col = lm = px,
// the same lane that computed w_c). No pack/unpack, no af staging.
// D layout: row = quad*4+reg = oc-within-16 (nt tile), col = lm = px.
// ---------------------------------------------------------------------------
__global__ __launch_bounds__(256, 3) void deform_kernel(const unsigned short* __restrict__ featp,
                                                        const float* __restrict__ offs,
                                                        const unsigned short* __restrict__ wtf,
                                                        const float* __restrict__ db,
                                                        float* __restrict__ out) {
    const int tid  = threadIdx.x;
    const int lane = tid & 63;
    const int wave = tid >> 6;
    const int lm   = lane & 15;
    const int quad = lane >> 4;

    const int bx = blockIdx.x;
    const int strip = ((bx & 7) << 8) | (bx >> 3);
    const int wo_base = (strip & 1) << 7;
    const int ho = (strip >> 1) & 255;
    const int b  = strip >> 9;

    const int wo0 = wo_base + wave * 32 + lm;       // mt=0 pixel; mt=1 is +16

    const float* opb = offs + (((size_t)b * 18) << 16) + (ho << 8) + wo0;
    const unsigned* fpq = (const unsigned*)featp + ((size_t)b << 21) + quad * 4;

    float4v acc[2][4];                  // [mt][nt]: rows=oc quad*4+r, col=px lm
#pragma unroll
    for (int mt = 0; mt < 2; mt++)
#pragma unroll
        for (int nt = 0; nt < 4; nt++) acc[mt][nt] = (float4v)0.f;

    float w00[2], w01[2], w10[2], w11[2];
    unsigned e00[2], e01[2], e10[2], e11[2];
    uint4v G[2][4][2];                  // [mt][corner][step], 16B each

#define COORDS(MT, KY, KX, OY, OX)                                               \
    {                                                                            \
        float sy = (float)(ho - 1 + (KY)) + (OY);                                \
        float sx = (float)(wo0 + (MT) * 16 - 1 + (KX)) + (OX);                   \
        float y0f = floorf(sy), x0f = floorf(sx);                                \
        float dy = sy - y0f, dx = sx - x0f;                                      \
        int y0 = (int)y0f, x0 = (int)x0f;                                        \
        float wy0 = ((unsigned)y0 < 256u) ? (1.f - dy) : 0.f;                    \
        float wy1 = ((unsigned)(y0 + 1) < 256u) ? dy : 0.f;                      \
        float wx0 = ((unsigned)x0 < 256u) ? (1.f - dx) : 0.f;                    \
        float wx1 = ((unsigned)(x0 + 1) < 256u) ? dx : 0.f;                      \
        int yb0 = y0 < 0 ? 0 : (y0 > 255 ? 255 : y0);                            \
        int yb1 = (y0 + 1) < 0 ? 0 : ((y0 + 1) > 255 ? 255 : (y0 + 1));          \
        int xb0 = x0 < 0 ? 0 : (x0 > 255 ? 255 : x0);                            \
        int xb1 = (x0 + 1) < 0 ? 0 : ((x0 + 1) > 255 ? 255 : (x0 + 1));          \
        w00[MT] = wy0 * wx0; w01[MT] = wy0 * wx1;                                \
        w10[MT] = wy1 * wx0; w11[MT] = wy1 * wx1;                                \
        e00[MT] = ((yb0 << 8) + xb0) << 5; e01[MT] = ((yb0 << 8) + xb1) << 5;    \
        e10[MT] = ((yb1 << 8) + xb0) << 5; e11[MT] = ((yb1 << 8) + xb1) << 5;    \
    }

#define ISSUE(MT)                                                                \
    {                                                                            \
        G[MT][0][0] = *(const uint4v*)(fpq + e00[MT]);                           \
        G[MT][0][1] = *(const uint4v*)(fpq + e00[MT] + 16);                      \
        G[MT][1][0] = *(const uint4v*)(fpq + e01[MT]);                           \
        G[MT][1][1] = *(const uint4v*)(fpq + e01[MT] + 16);                      \
        G[MT][2][0] = *(const uint4v*)(fpq + e10[MT]);                           \
        G[MT][2][1] = *(const uint4v*)(fpq + e10[MT] + 16);                      \
        G[MT][3][0] = *(const uint4v*)(fpq + e11[MT]);                           \
        G[MT][3][1] = *(const uint4v*)(fpq + e11[MT] + 16);                      \
    }

// Per corner: tmp[nt] = W_tap · feat_corner (K=64 over both steps), then
// acc[MT][nt] += w_corner * tmp[nt]. All lane-local (D col = lm = px).
#define MFMA_CORNERS(MT)                                                         \
    _Pragma("unroll")                                                            \
    for (int c = 0; c < 4; c++) {                                                \
        union { uint4v u; short8 v; } gb0, gb1;                                  \
        gb0.u = G[MT][c][0]; gb1.u = G[MT][c][1];                                \
        const float wc = (c == 0) ? w00[MT] : (c == 1) ? w01[MT]                 \
                       : (c == 2) ? w10[MT] : w11[MT];                           \
        float4v t0, t1, t2, t3;                                                  \
        t0 = __builtin_amdgcn_mfma_f32_16x16x32_bf16(bfr[0][0], gb0.v, (float4v)0.f, 0, 0, 0); \
        t1 = __builtin_amdgcn_mfma_f32_16x16x32_bf16(bfr[0][1], gb0.v, (float4v)0.f, 0, 0, 0); \
        t2 = __builtin_amdgcn_mfma_f32_16x16x32_bf16(bfr[0][2], gb0.v, (float4v)0.f, 0, 0, 0); \
        t3 = __builtin_amdgcn_mfma_f32_16x16x32_bf16(bfr[0][3], gb0.v, (float4v)0.f, 0, 0, 0); \
        t0 = __builtin_amdgcn_mfma_f32_16x16x32_bf16(bfr[1][0], gb1.v, t0, 0, 0, 0); \
        t1 = __builtin_amdgcn_mfma_f32_16x16x32_bf16(bfr[1][1], gb1.v, t1, 0, 0, 0); \
        t2 = __builtin_amdgcn_mfma_f32_16x16x32_bf16(bfr[1][2], gb1.v, t2, 0, 0, 0); \
        t3 = __builtin_amdgcn_mfma_f32_16x16x32_bf16(bfr[1][3], gb1.v, t3, 0, 0, 0); \
        _Pragma("unroll")                                                        \
        for (int r = 0; r < 4; r++) {                                            \
            acc[MT][0][r] += wc * t0[r];                                         \
            acc[MT][1][r] += wc * t1[r];                                         \
            acc[MT][2][r] += wc * t2[r];                                         \
            acc[MT][3][r] += wc * t3[r];                                         \
        }                                                                        \
    }

    // Prologue: gather tap 0 for both mt
    {
        float oy0 = opb[0],  ox0 = opb[65536];
        float oy1 = opb[16], ox1 = opb[65536 + 16];
        COORDS(0, 0, 0, oy0, ox0);
        ISSUE(0);
        COORDS(1, 0, 0, oy1, ox1);
        ISSUE(1);
    }

    for (int tap = 0; tap < 9; ++tap) {
        float ny0 = 0.f, nx0 = 0.f, ny1 = 0.f, nx1 = 0.f;
        if (tap < 8) {                                  // next-tap offsets, early
            const float* p = opb + ((size_t)(2 * tap + 2) << 16);
            ny0 = p[0]; ny1 = p[16];
            nx0 = p[65536]; nx1 = p[65536 + 16];
        }
        short8 bfr[2][4];                               // W frags (A-side now)
        {
            const unsigned short* wp = wtf + (size_t)tap * 4096 + lane * 8;
#pragma unroll
            for (int nt = 0; nt < 4; nt++) {
                bfr[0][nt] = *(const short8*)(wp + (nt << 9));
                bfr[1][nt] = *(const short8*)(wp + 2048 + (nt << 9));
            }
        }
        const int tn  = tap + 1;
        const int nky = (int)((unsigned)tn / 3u);
        const int nkx = tn - 3 * nky;

        MFMA_CORNERS(0);                                // consumes G[0] (issued last tap)
        if (tap < 8) { COORDS(0, nky, nkx, ny0, nx0); ISSUE(0); }
        MFMA_CORNERS(1);                                // consumes G[1]
        if (tap < 8) { COORDS(1, nky, nkx, ny1, nx1); ISSUE(1); }
    }

    // Store out^T fragments: oc = nt*16 + quad*4 + r, px = wo0 (+16 for mt=1)
#pragma unroll
    for (int nt = 0; nt < 4; nt++) {
        const int oc0 = nt * 16 + quad * 4;
        float4 bv = *(const float4*)(db + oc0);
        float* op = out + (((size_t)(b * 64 + oc0)) << 16) + (ho << 8);
#pragma unroll
        for (int r = 0; r < 4; r++) {
            float* q = op + ((size_t)r << 16);
            float bvr = (r == 0) ? bv.x : (r == 1) ? bv.y : (r == 2) ? bv.z : bv.w;
            q[wo0]      = acc[0][nt][r] + bvr;
            q[wo0 + 16] = acc[1][nt][r] + bvr;
        }
    }
#undef COORDS
#undef ISSUE
#undef MFMA_CORNERS
}

// ---------------------------------------------------------------------------
extern "C" void kernel_launch(void* const* d_in, const int* in_sizes, int n_in,
                              void* d_out, int out_size, void* d_ws, size_t ws_size,
                              hipStream_t stream) {
    const float* x  = (const float*)d_in[0];
    const float* cw = (const float*)d_in[1];
    const float* cb = (const float*)d_in[2];
    const float* ow = (const float*)d_in[3];
    const float* ob = (const float*)d_in[4];
    const float* dw = (const float*)d_in[5];
    const float* db = (const float*)d_in[6];
    float* out = (float*)d_out;

    unsigned short* featp = (unsigned short*)d_ws;       // 33.5 MB bf16 NHWC
    float* offsb = (float*)(featp + FEAT_N);             // 18 MB
    unsigned short* wtf  = (unsigned short*)(offsb + OFFS_N);  // 72 KB
    unsigned short* wt2f = wtf + WTF_N;                  // 36 KB

    prep_weights<<<216, 256, 0, stream>>>(dw, ow, wtf, wt2f);
    conv1_kernel<<<1024, 256, 0, stream>>>(x, cw, cb, featp);
    conv2_kernel<<<2048, 256, 0, stream>>>(featp, wt2f, ob, offsb);
    deform_kernel<<<2048, 256, 0, stream>>>(featp, offsb, wtf, db, out);
}

// Round 7
// 294.707 us; speedup vs baseline: 1.4231x; 1.4231x over previous
//
#include <hip/hip_runtime.h>
#include <hip/hip_bf16.h>

// Problem constants: B=4, H=W=256, C=64, OC=64, K=3, PAD=1
#define FEAT_N (4*64*256*256)
#define OFFS_N (4*18*256*256)
#define WTF_N  (576*64)            // deform weights, bf16, MFMA-B-fragment order
#define WT2F_N (576*32)            // offset-conv weights, bf16 frags, N padded to 32

typedef __attribute__((ext_vector_type(8))) short short8;
typedef __attribute__((ext_vector_type(4))) float float4v;
typedef __attribute__((ext_vector_type(4))) unsigned uint4v;

__device__ __forceinline__ unsigned short f2bf(float f) {
    union { float f; unsigned u; } c; c.f = f;
    unsigned r = c.u + 0x7FFF + ((c.u >> 16) & 1);   // RNE
    return (unsigned short)(r >> 16);
}

__device__ __forceinline__ unsigned pack_bf16x2(float lo, float hi) {
    float2 v; v.x = lo; v.y = hi;
    __hip_bfloat162 h = __float22bfloat162_rn(v);
    union { __hip_bfloat162 h; unsigned u; } c; c.h = h;
    return c.u;
}

__device__ __forceinline__ float bf_lo(unsigned u) { return __uint_as_float(u << 16); }
__device__ __forceinline__ float bf_hi(unsigned u) { return __uint_as_float(u & 0xFFFF0000u); }

// ---------------------------------------------------------------------------
// Weight prep (EXACT R4): deform weights -> wtf (B-frags, 4 N-tiles);
// offset-conv weights -> wt2f (B-frags, 2 N-tiles, oc>=18 zero).
// ---------------------------------------------------------------------------
__global__ __launch_bounds__(256) void prep_weights(const float* __restrict__ dw,
                                                    const float* __restrict__ ow,
                                                    unsigned short* __restrict__ wtf,
                                                    unsigned short* __restrict__ wt2f) {
    int idx = blockIdx.x * 256 + threadIdx.x;
    if (idx < WTF_N) {
        int j    = idx & 7;
        int lane = (idx >> 3) & 63;
        int nt   = (idx >> 9) & 3;
        int ks   = idx >> 11;
        int k    = ks * 32 + ((lane >> 4) << 3) + j;
        int tap  = k >> 6;
        int ic   = k & 63;
        int n    = nt * 16 + (lane & 15);
        wtf[idx] = f2bf(dw[n * 576 + ic * 9 + tap]);
    }
    int i2 = idx - WTF_N;
    if (i2 >= 0 && i2 < WT2F_N) {
        int j    = i2 & 7;
        int lane = (i2 >> 3) & 63;
        int nt   = (i2 >> 9) & 1;
        int ks   = i2 >> 10;
        int k    = ks * 32 + ((lane >> 4) << 3) + j;
        int tap  = k >> 6;
        int ic   = k & 63;
        int n    = nt * 16 + (lane & 15);
        wt2f[i2] = (n < 18) ? f2bf(ow[n * 576 + ic * 9 + tap]) : (unsigned short)0;
    }
}

// ---------------------------------------------------------------------------
// conv1 (EXACT R4, known-pass): x[4,3,256,256] * w + b -> featp, NHWC bf16:
// dword index for (b,y,x,cp) = ((b<<16)+(y<<8)+x)*32 + cp.
// ---------------------------------------------------------------------------
__global__ __launch_bounds__(256) void conv1_kernel(const float* __restrict__ x,
                                                    const float* __restrict__ cw,
                                                    const float* __restrict__ cb,
                                                    unsigned short* __restrict__ featp) {
    __shared__ __align__(16) float wl[64 * 28];
    __shared__ float bl[64];
    const int tid = threadIdx.x;
    for (int i = tid; i < 64 * 28; i += 256) {
        int oc = i / 28;
        int t  = i - oc * 28;
        wl[i] = (t < 27) ? cw[oc * 27 + t] : 0.f;
    }
    if (tid < 64) bl[tid] = cb[tid];
    __syncthreads();

    const int bx = blockIdx.x;
    const int b  = bx >> 8;
    const int h  = bx & 255;
    const int w  = tid;

    float xr[3][3][3];
#pragma unroll
    for (int ic = 0; ic < 3; ic++) {
#pragma unroll
        for (int r = 0; r < 3; r++) {
            int row = h - 1 + r;
            bool rok = (unsigned)row < 256u;
#pragma unroll
            for (int j = 0; j < 3; j++) {
                int col = w - 1 + j;
                bool ok = rok && ((unsigned)col < 256u);
                xr[ic][r][j] = ok ? x[((b * 3 + ic) << 16) + (row << 8) + col] : 0.f;
            }
        }
    }

    unsigned* dst = (unsigned*)featp + ((((size_t)b << 16) + (h << 8) + w) << 5);
    for (int g = 0; g < 8; g++) {               // dynamic: keep code compact
        uint4v v;
#pragma unroll
        for (int q = 0; q < 4; q++) {
            const int ocp = 4 * g + q;
            float a0 = bl[2 * ocp], a1 = bl[2 * ocp + 1];
            const float* wp0 = &wl[(2 * ocp) * 28];
            const float* wp1 = wp0 + 28;
#pragma unroll
            for (int ic = 0; ic < 3; ic++)
#pragma unroll
                for (int i = 0; i < 3; i++)
#pragma unroll
                    for (int j = 0; j < 3; j++) {
                        float xv = xr[ic][i][j];
                        a0 += xv * wp0[ic * 9 + i * 3 + j];
                        a1 += xv * wp1[ic * 9 + i * 3 + j];
                    }
            v[q] = pack_bf16x2(a0, a1);
        }
        *(uint4v*)(dst + 4 * g) = v;
    }
}

// ---------------------------------------------------------------------------
// FUSED conv2 + deform. Same strip decode as the (passing) standalone R4
// kernels; wave w's conv2 output pixels == wave w's deform input pixels, so
// the exchange is intra-wave via LDS offl[wave][oc][pxw] (stride-33 padded,
// conflict-free) and needs NO barrier. Phase 1 = R4 conv2 body with the
// global store redirected to LDS (+bias). Phase 2 = R4 deform body with the
// offset loads redirected from global offs to LDS. Everything else is
// byte-identical to the proven R4 kernels.
// ---------------------------------------------------------------------------
__global__ __launch_bounds__(256, 3) void fused_kernel(const unsigned short* __restrict__ featp,
                                                       const unsigned short* __restrict__ wt2f,
                                                       const float* __restrict__ ob,
                                                       const unsigned short* __restrict__ wtf,
                                                       const float* __restrict__ db,
                                                       float* __restrict__ out) {
    __shared__ float offl[4][18 * 33];   // [wave][oc*33 + pxw], 9504 B

    const int tid  = threadIdx.x;
    const int lane = tid & 63;
    const int wave = tid >> 6;
    const int lm   = lane & 15;
    const int quad = lane >> 4;

    const int bx = blockIdx.x;
    const int strip = ((bx & 7) << 8) | (bx >> 3);
    const int wo_base = (strip & 1) << 7;
    const int ho = (strip >> 1) & 255;
    const int b  = strip >> 9;

    const unsigned* fpq = (const unsigned*)featp + ((size_t)b << 21) + quad * 4;
    const int colb = wo_base + wave * 32 + lm;
    float* offw = &offl[wave][0];

    // ================= PHASE 1: offset conv (R4 conv2 body) =================
    {
        float4v acc[2][2];
#pragma unroll
        for (int mt = 0; mt < 2; mt++)
#pragma unroll
            for (int nt = 0; nt < 2; nt++) acc[mt][nt] = (float4v)0.f;

        uint4v A[2][2];

#define C2LOAD(KY, KX, DST)                                                      \
    {                                                                            \
        const int row = ho - 1 + (KY);                                           \
        const bool rok = (unsigned)row < 256u;                                   \
        _Pragma("unroll")                                                        \
        for (int mt = 0; mt < 2; mt++) {                                         \
            const int col = colb + mt * 16 + (KX) - 1;                           \
            DST[mt][0] = (uint4v)0;                                              \
            DST[mt][1] = (uint4v)0;                                              \
            if (rok && (unsigned)col < 256u) {                                   \
                const unsigned* p = fpq + (((row << 8) + col) << 5);             \
                DST[mt][0] = *(const uint4v*)p;                                  \
                DST[mt][1] = *(const uint4v*)(p + 16);                           \
            }                                                                    \
        }                                                                        \
    }

        C2LOAD(0, 0, A);

#pragma unroll
        for (int tap = 0; tap < 9; tap++) {
            short8 bfr[2][2];
            const unsigned short* wp = wt2f + (size_t)(tap * 2) * 1024 + lane * 8;
#pragma unroll
            for (int st = 0; st < 2; st++) {
                bfr[st][0] = *(const short8*)(wp + st * 1024);
                bfr[st][1] = *(const short8*)(wp + st * 1024 + 512);
            }
            uint4v N[2][2];
            if (tap < 8) {
                const int tn  = tap + 1;
                const int tky = tn / 3;
                const int tkx = tn - 3 * tky;
                C2LOAD(tky, tkx, N);
            }
#pragma unroll
            for (int mt = 0; mt < 2; mt++) {
                union { short8 v; uint4v u; } f0, f1;
                f0.u = A[mt][0]; f1.u = A[mt][1];
                acc[mt][0] = __builtin_amdgcn_mfma_f32_16x16x32_bf16(f0.v, bfr[0][0], acc[mt][0], 0, 0, 0);
                acc[mt][1] = __builtin_amdgcn_mfma_f32_16x16x32_bf16(f0.v, bfr[0][1], acc[mt][1], 0, 0, 0);
                acc[mt][0] = __builtin_amdgcn_mfma_f32_16x16x32_bf16(f1.v, bfr[1][0], acc[mt][0], 0, 0, 0);
                acc[mt][1] = __builtin_amdgcn_mfma_f32_16x16x32_bf16(f1.v, bfr[1][1], acc[mt][1], 0, 0, 0);
            }
            if (tap < 8) {
#pragma unroll
                for (int mt = 0; mt < 2; mt++) {
                    A[mt][0] = N[mt][0];
                    A[mt][1] = N[mt][1];
                }
            }
        }
#undef C2LOAD

        // Store offsets to per-wave LDS (was: global offs). pxw = mt*16+quad*4+r.
#pragma unroll
        for (int nt = 0; nt < 2; nt++) {
            int oc = nt * 16 + lm;
            if (oc < 18) {
                float bv = ob[oc];
#pragma unroll
                for (int mt = 0; mt < 2; mt++) {
#pragma unroll
                    for (int r = 0; r < 4; r++)
                        offw[oc * 33 + mt * 16 + quad * 4 + r] = acc[mt][nt][r] + bv;
                }
            }
        }
    }
    // Intra-wave producer/consumer: compiler-inserted lgkmcnt ordering is
    // sufficient (each wave reads only its own offl[wave] region).

    // ================= PHASE 2: deform conv (R4 deform body) ================
    const int wo0 = wo_base + wave * 32 + lm;       // mt=0 pixel; mt=1 is +16

    float4v acc[2][4];
#pragma unroll
    for (int mt = 0; mt < 2; mt++)
#pragma unroll
        for (int nt = 0; nt < 4; nt++) acc[mt][nt] = (float4v)0.f;

    float w00[2], w01[2], w10[2], w11[2];
    unsigned e00[2], e01[2], e10[2], e11[2];
    uint4v G[2][4][2];                  // [mt][corner][step], 16B each

    union AFU { short8 v; unsigned u[4]; };

#define COORDS(MT, KY, KX, OY, OX)                                               \
    {                                                                            \
        float sy = (float)(ho - 1 + (KY)) + (OY);                                \
        float sx = (float)(wo0 + (MT) * 16 - 1 + (KX)) + (OX);                   \
        float y0f = floorf(sy), x0f = floorf(sx);                                \
        float dy = sy - y0f, dx = sx - x0f;                                      \
        int y0 = (int)y0f, x0 = (int)x0f;                                        \
        float wy0 = ((unsigned)y0 < 256u) ? (1.f - dy) : 0.f;                    \
        float wy1 = ((unsigned)(y0 + 1) < 256u) ? dy : 0.f;                      \
        float wx0 = ((unsigned)x0 < 256u) ? (1.f - dx) : 0.f;                    \
        float wx1 = ((unsigned)(x0 + 1) < 256u) ? dx : 0.f;                      \
        int yb0 = y0 < 0 ? 0 : (y0 > 255 ? 255 : y0);                            \
        int yb1 = (y0 + 1) < 0 ? 0 : ((y0 + 1) > 255 ? 255 : (y0 + 1));          \
        int xb0 = x0 < 0 ? 0 : (x0 > 255 ? 255 : x0);                            \
        int xb1 = (x0 + 1) < 0 ? 0 : ((x0 + 1) > 255 ? 255 : (x0 + 1));          \
        w00[MT] = wy0 * wx0; w01[MT] = wy0 * wx1;                                \
        w10[MT] = wy1 * wx0; w11[MT] = wy1 * wx1;                                \
        e00[MT] = ((yb0 << 8) + xb0) << 5; e01[MT] = ((yb0 << 8) + xb1) << 5;    \
        e10[MT] = ((yb1 << 8) + xb0) << 5; e11[MT] = ((yb1 << 8) + xb1) << 5;    \
    }

#define ISSUE(MT)                                                                \
    {                                                                            \
        G[MT][0][0] = *(const uint4v*)(fpq + e00[MT]);                           \
        G[MT][0][1] = *(const uint4v*)(fpq + e00[MT] + 16);                      \
        G[MT][1][0] = *(const uint4v*)(fpq + e01[MT]);                           \
        G[MT][1][1] = *(const uint4v*)(fpq + e01[MT] + 16);                      \
        G[MT][2][0] = *(const uint4v*)(fpq + e10[MT]);                           \
        G[MT][2][1] = *(const uint4v*)(fpq + e10[MT] + 16);                      \
        G[MT][3][0] = *(const uint4v*)(fpq + e11[MT]);                           \
        G[MT][3][1] = *(const uint4v*)(fpq + e11[MT] + 16);                      \
    }

#define COMBINE(MT, AF)                                                          \
    _Pragma("unroll")                                                            \
    for (int st = 0; st < 2; st++) {                                             \
        _Pragma("unroll")                                                        \
        for (int j = 0; j < 4; j++) {                                            \
            unsigned u0 = G[MT][0][st][j], u1 = G[MT][1][st][j];                 \
            unsigned u2 = G[MT][2][st][j], u3 = G[MT][3][st][j];                 \
            float g0 = w00[MT] * bf_lo(u0) + w01[MT] * bf_lo(u1)                 \
                     + w10[MT] * bf_lo(u2) + w11[MT] * bf_lo(u3);                \
            float g1 = w00[MT] * bf_hi(u0) + w01[MT] * bf_hi(u1)                 \
                     + w10[MT] * bf_hi(u2) + w11[MT] * bf_hi(u3);                \
            AF[st].u[j] = pack_bf16x2(g0, g1);                                   \
        }                                                                        \
    }

#define MFMA_MT(MT, AF)                                                          \
    _Pragma("unroll")                                                            \
    for (int nt = 0; nt < 4; nt++)                                               \
        acc[MT][nt] = __builtin_amdgcn_mfma_f32_16x16x32_bf16(                   \
            AF[0].v, bfr[0][nt], acc[MT][nt], 0, 0, 0);                          \
    _Pragma("unroll")                                                            \
    for (int nt = 0; nt < 4; nt++)                                               \
        acc[MT][nt] = __builtin_amdgcn_mfma_f32_16x16x32_bf16(                   \
            AF[1].v, bfr[1][nt], acc[MT][nt], 0, 0, 0);

    // Prologue: gather tap 0 for both mt (offsets now from LDS)
    {
        float oy0 = offw[0 * 33 + lm],      ox0 = offw[1 * 33 + lm];
        float oy1 = offw[0 * 33 + lm + 16], ox1 = offw[1 * 33 + lm + 16];
        COORDS(0, 0, 0, oy0, ox0);
        ISSUE(0);
        COORDS(1, 0, 0, oy1, ox1);
        ISSUE(1);
    }

    for (int tap = 0; tap < 9; ++tap) {
        float ny0 = 0.f, nx0 = 0.f, ny1 = 0.f, nx1 = 0.f;
        if (tap < 8) {                                  // next-tap offsets, early
            const float* p = offw + (2 * tap + 2) * 33;
            ny0 = p[lm];      ny1 = p[lm + 16];
            nx0 = p[33 + lm]; nx1 = p[33 + lm + 16];
        }
        short8 bfr[2][4];                               // B-frags, both steps
        {
            const unsigned short* wp = wtf + (size_t)tap * 4096 + lane * 8;
#pragma unroll
            for (int nt = 0; nt < 4; nt++) {
                bfr[0][nt] = *(const short8*)(wp + (nt << 9));
                bfr[1][nt] = *(const short8*)(wp + 2048 + (nt << 9));
            }
        }
        const int tn  = tap + 1;
        const int nky = (int)((unsigned)tn / 3u);
        const int nkx = tn - 3 * nky;

        AFU af[2];
        COMBINE(0, af);                                 // G0 issued last tap
        MFMA_MT(0, af);
        if (tap < 8) { COORDS(0, nky, nkx, ny0, nx0); ISSUE(0); }
        COMBINE(1, af);                                 // G1 issued last tap
        MFMA_MT(1, af);
        if (tap < 8) { COORDS(1, nky, nkx, ny1, nx1); ISSUE(1); }
    }

#pragma unroll
    for (int nt = 0; nt < 4; nt++) {
        int oc = nt * 16 + lm;
        float bv = db[oc];
        float* op = out + (((size_t)(b * 64 + oc)) << 16) + (ho << 8)
                  + wo_base + wave * 32 + quad * 4;
#pragma unroll
        for (int mt = 0; mt < 2; mt++) {
            float4 v = {acc[mt][nt][0] + bv, acc[mt][nt][1] + bv,
                        acc[mt][nt][2] + bv, acc[mt][nt][3] + bv};
            *(float4*)(op + mt * 16) = v;
        }
    }
#undef COORDS
#undef ISSUE
#undef COMBINE
#undef MFMA_MT
}

// ---------------------------------------------------------------------------
extern "C" void kernel_launch(void* const* d_in, const int* in_sizes, int n_in,
                              void* d_out, int out_size, void* d_ws, size_t ws_size,
                              hipStream_t stream) {
    const float* x  = (const float*)d_in[0];
    const float* cw = (const float*)d_in[1];
    const float* cb = (const float*)d_in[2];
    const float* ow = (const float*)d_in[3];
    const float* ob = (const float*)d_in[4];
    const float* dw = (const float*)d_in[5];
    const float* db = (const float*)d_in[6];
    float* out = (float*)d_out;

    unsigned short* featp = (unsigned short*)d_ws;       // 33.5 MB bf16 NHWC
    float* offsb = (float*)(featp + FEAT_N);             // (unused after fusion)
    unsigned short* wtf  = (unsigned short*)(offsb + OFFS_N);  // 72 KB
    unsigned short* wt2f = wtf + WTF_N;                  // 36 KB

    prep_weights<<<216, 256, 0, stream>>>(dw, ow, wtf, wt2f);
    conv1_kernel<<<1024, 256, 0, stream>>>(x, cw, cb, featp);
    fused_kernel<<<2048, 256, 0, stream>>>(featp, wt2f, ob, wtf, db, out);
}

// Round 8
// 278.463 us; speedup vs baseline: 1.5061x; 1.0583x over previous
//
#include <hip/hip_runtime.h>
#include <hip/hip_bf16.h>

// Problem constants: B=4, H=W=256, C=64, OC=64, K=3, PAD=1
#define FEAT_N (4*64*256*256)
#define OFFS_N (4*18*256*256)
#define WTF_N  (576*64)            // deform weights, bf16, MFMA-B-fragment order
#define WT2F_N (576*32)            // offset-conv weights, bf16 frags, N padded to 32
#define WT1F_N (4*64*8)            // conv1 weights, bf16 B-frags, K=32 (27 real), N=64

typedef __attribute__((ext_vector_type(8))) short short8;
typedef __attribute__((ext_vector_type(4))) float float4v;
typedef __attribute__((ext_vector_type(4))) unsigned uint4v;

__device__ __forceinline__ unsigned short f2bf(float f) {
    union { float f; unsigned u; } c; c.f = f;
    unsigned r = c.u + 0x7FFF + ((c.u >> 16) & 1);   // RNE
    return (unsigned short)(r >> 16);
}

__device__ __forceinline__ unsigned pack_bf16x2(float lo, float hi) {
    float2 v; v.x = lo; v.y = hi;
    __hip_bfloat162 h = __float22bfloat162_rn(v);
    union { __hip_bfloat162 h; unsigned u; } c; c.h = h;
    return c.u;
}

__device__ __forceinline__ float bf_lo(unsigned u) { return __uint_as_float(u << 16); }
__device__ __forceinline__ float bf_hi(unsigned u) { return __uint_as_float(u & 0xFFFF0000u); }

// ---------------------------------------------------------------------------
// Weight prep: R4 body + third branch for conv1 B-frags (wt1f).
// wt1f idx = (nt<<9)+(lane<<3)+j ; n = nt*16+(lane&15); k = (lane>>4)*8+j;
// val = k<27 ? cw[n*27+k] : 0.   (grid 224 blocks: 57344 = 55296 + 2048)
// ---------------------------------------------------------------------------
__global__ __launch_bounds__(256) void prep_weights(const float* __restrict__ dw,
                                                    const float* __restrict__ ow,
                                                    const float* __restrict__ cw,
                                                    unsigned short* __restrict__ wtf,
                                                    unsigned short* __restrict__ wt2f,
                                                    unsigned short* __restrict__ wt1f) {
    int idx = blockIdx.x * 256 + threadIdx.x;
    if (idx < WTF_N) {
        int j    = idx & 7;
        int lane = (idx >> 3) & 63;
        int nt   = (idx >> 9) & 3;
        int ks   = idx >> 11;
        int k    = ks * 32 + ((lane >> 4) << 3) + j;
        int tap  = k >> 6;
        int ic   = k & 63;
        int n    = nt * 16 + (lane & 15);
        wtf[idx] = f2bf(dw[n * 576 + ic * 9 + tap]);
    }
    int i2 = idx - WTF_N;
    if (i2 >= 0 && i2 < WT2F_N) {
        int j    = i2 & 7;
        int lane = (i2 >> 3) & 63;
        int nt   = (i2 >> 9) & 1;
        int ks   = i2 >> 10;
        int k    = ks * 32 + ((lane >> 4) << 3) + j;
        int tap  = k >> 6;
        int ic   = k & 63;
        int n    = nt * 16 + (lane & 15);
        wt2f[i2] = (n < 18) ? f2bf(ow[n * 576 + ic * 9 + tap]) : (unsigned short)0;
    }
    int i3 = idx - WTF_N - WT2F_N;
    if (i3 >= 0 && i3 < WT1F_N) {
        int j    = i3 & 7;
        int lane = (i3 >> 3) & 63;
        int nt   = (i3 >> 9) & 3;
        int n    = nt * 16 + (lane & 15);
        int k    = ((lane >> 4) << 3) + j;
        wt1f[i3] = (k < 27) ? f2bf(cw[n * 27 + k]) : (unsigned short)0;
    }
}

// ---------------------------------------------------------------------------
// conv1 v2: MFMA im2col GEMM. M = 256 px (one row/block), N = 64 oc, K = 32
// (27 taps + 5 zero-pad). x row-halo staged in LDS as bf16 with zero borders
// and a zero pad-row; A-frag = 8 ds_read_u16 + 4 packs per 16-px tile;
// B-frags (wt1f) live in 16 VGPR, loaded once. Same A/B/D orientation as the
// proven conv2 MFMA path (D: col=lm=oc, row=quad*4+r=px).
// Output featp NHWC bf16, ushort index = pixel_lin*64 + oc (identical layout
// to R4/R7 conv1 output).
// ---------------------------------------------------------------------------
__global__ __launch_bounds__(256) void conv1_kernel(const float* __restrict__ x,
                                                    const unsigned short* __restrict__ wt1f,
                                                    const float* __restrict__ cb,
                                                    unsigned short* __restrict__ featp) {
    __shared__ unsigned short xs[10 * 264];   // rows 0..8 = (ic*3+ti), row 9 = zeros
    const int tid  = threadIdx.x;
    const int lane = tid & 63;
    const int wave = tid >> 6;
    const int lm   = lane & 15;
    const int quad = lane >> 4;

    const int bx = blockIdx.x;
    const int b  = bx >> 8;
    const int h  = bx & 255;

    // ---- stage x halo rows (bf16, zero borders) ----
#pragma unroll
    for (int r = 0; r < 9; r++) {
        const int ic = r / 3, ti = r % 3;                 // static
        const int srow = h - 1 + ti;
        const bool rok = (unsigned)srow < 256u;
        const float* xrow = x + ((b * 3 + ic) << 16) + (srow << 8);
        {
            const int c = tid;                            // c=0..255
            float v = (rok && (unsigned)(c - 1) < 256u) ? xrow[c - 1] : 0.f;
            xs[r * 264 + c] = f2bf(v);
        }
        if (tid < 2) {
            const int c = tid + 256;                      // c=256,257
            float v = (rok && (unsigned)(c - 1) < 256u) ? xrow[c - 1] : 0.f;
            xs[r * 264 + c] = f2bf(v);
        }
    }
    xs[9 * 264 + tid] = 0;
    if (tid < 8) xs[9 * 264 + 256 + tid] = 0;
    __syncthreads();

    // ---- per-lane A-offsets: k = quad*8+j -> xs row k/3, col-offset k%3 ----
    int off[8];
#pragma unroll
    for (int j = 0; j < 8; j++) {
        const int k = quad * 8 + j;
        const int row = (k < 27) ? (k / 3) : 9;
        const int tj  = (k < 27) ? (k - row * 3) : 0;
        off[j] = row * 264 + tj;
    }

    // ---- B-frags + bias, loaded once ----
    short8 bw[4];
#pragma unroll
    for (int nt = 0; nt < 4; nt++)
        bw[nt] = *(const short8*)(wt1f + nt * 512 + lane * 8);
    float bias[4];
#pragma unroll
    for (int nt = 0; nt < 4; nt++) bias[nt] = cb[nt * 16 + lm];

    unsigned short* fpx = featp + ((((size_t)b << 16) + (h << 8)) << 6);  // +px*64+oc

#pragma unroll
    for (int mt = 0; mt < 4; mt++) {
        const int px = wave * 64 + mt * 16 + lm;          // A-row pixel for this lane
        union { short8 v; unsigned u[4]; } af;
#pragma unroll
        for (int jj = 0; jj < 4; jj++) {
            unsigned lo = xs[off[2 * jj]     + px];
            unsigned hi = xs[off[2 * jj + 1] + px];
            af.u[jj] = lo | (hi << 16);
        }
        float4v d[4];
#pragma unroll
        for (int nt = 0; nt < 4; nt++)
            d[nt] = __builtin_amdgcn_mfma_f32_16x16x32_bf16(af.v, bw[nt], (float4v)0.f, 0, 0, 0);

        const int pxs = wave * 64 + mt * 16 + quad * 4;   // D-row pixel base
#pragma unroll
        for (int r = 0; r < 4; r++) {
            unsigned short* sp = fpx + (size_t)(pxs + r) * 64 + lm;
#pragma unroll
            for (int nt = 0; nt < 4; nt++)
                sp[nt * 16] = f2bf(d[nt][r] + bias[nt]);
        }
    }
}

// ---------------------------------------------------------------------------
// FUSED conv2 + deform (EXACT R7, known-pass).
// ---------------------------------------------------------------------------
__global__ __launch_bounds__(256, 3) void fused_kernel(const unsigned short* __restrict__ featp,
                                                       const unsigned short* __restrict__ wt2f,
                                                       const float* __restrict__ ob,
                                                       const unsigned short* __restrict__ wtf,
                                                       const float* __restrict__ db,
                                                       float* __restrict__ out) {
    __shared__ float offl[4][18 * 33];   // [wave][oc*33 + pxw], 9504 B

    const int tid  = threadIdx.x;
    const int lane = tid & 63;
    const int wave = tid >> 6;
    const int lm   = lane & 15;
    const int quad = lane >> 4;

    const int bx = blockIdx.x;
    const int strip = ((bx & 7) << 8) | (bx >> 3);
    const int wo_base = (strip & 1) << 7;
    const int ho = (strip >> 1) & 255;
    const int b  = strip >> 9;

    const unsigned* fpq = (const unsigned*)featp + ((size_t)b << 21) + quad * 4;
    const int colb = wo_base + wave * 32 + lm;
    float* offw = &offl[wave][0];

    // ================= PHASE 1: offset conv (R4 conv2 body) =================
    {
        float4v acc[2][2];
#pragma unroll
        for (int mt = 0; mt < 2; mt++)
#pragma unroll
            for (int nt = 0; nt < 2; nt++) acc[mt][nt] = (float4v)0.f;

        uint4v A[2][2];

#define C2LOAD(KY, KX, DST)                                                      \
    {                                                                            \
        const int row = ho - 1 + (KY);                                           \
        const bool rok = (unsigned)row < 256u;                                   \
        _Pragma("unroll")                                                        \
        for (int mt = 0; mt < 2; mt++) {                                         \
            const int col = colb + mt * 16 + (KX) - 1;                           \
            DST[mt][0] = (uint4v)0;                                              \
            DST[mt][1] = (uint4v)0;                                              \
            if (rok && (unsigned)col < 256u) {                                   \
                const unsigned* p = fpq + (((row << 8) + col) << 5);             \
                DST[mt][0] = *(const uint4v*)p;                                  \
                DST[mt][1] = *(const uint4v*)(p + 16);                           \
            }                                                                    \
        }                                                                        \
    }

        C2LOAD(0, 0, A);

#pragma unroll
        for (int tap = 0; tap < 9; tap++) {
            short8 bfr[2][2];
            const unsigned short* wp = wt2f + (size_t)(tap * 2) * 1024 + lane * 8;
#pragma unroll
            for (int st = 0; st < 2; st++) {
                bfr[st][0] = *(const short8*)(wp + st * 1024);
                bfr[st][1] = *(const short8*)(wp + st * 1024 + 512);
            }
            uint4v N[2][2];
            if (tap < 8) {
                const int tn  = tap + 1;
                const int tky = tn / 3;
                const int tkx = tn - 3 * tky;
                C2LOAD(tky, tkx, N);
            }
#pragma unroll
            for (int mt = 0; mt < 2; mt++) {
                union { short8 v; uint4v u; } f0, f1;
                f0.u = A[mt][0]; f1.u = A[mt][1];
                acc[mt][0] = __builtin_amdgcn_mfma_f32_16x16x32_bf16(f0.v, bfr[0][0], acc[mt][0], 0, 0, 0);
                acc[mt][1] = __builtin_amdgcn_mfma_f32_16x16x32_bf16(f0.v, bfr[0][1], acc[mt][1], 0, 0, 0);
                acc[mt][0] = __builtin_amdgcn_mfma_f32_16x16x32_bf16(f1.v, bfr[1][0], acc[mt][0], 0, 0, 0);
                acc[mt][1] = __builtin_amdgcn_mfma_f32_16x16x32_bf16(f1.v, bfr[1][1], acc[mt][1], 0, 0, 0);
            }
            if (tap < 8) {
#pragma unroll
                for (int mt = 0; mt < 2; mt++) {
                    A[mt][0] = N[mt][0];
                    A[mt][1] = N[mt][1];
                }
            }
        }
#undef C2LOAD

        // Store offsets to per-wave LDS (was: global offs). pxw = mt*16+quad*4+r.
#pragma unroll
        for (int nt = 0; nt < 2; nt++) {
            int oc = nt * 16 + lm;
            if (oc < 18) {
                float bv = ob[oc];
#pragma unroll
                for (int mt = 0; mt < 2; mt++) {
#pragma unroll
                    for (int r = 0; r < 4; r++)
                        offw[oc * 33 + mt * 16 + quad * 4 + r] = acc[mt][nt][r] + bv;
                }
            }
        }
    }
    // Intra-wave producer/consumer: compiler-inserted lgkmcnt ordering is
    // sufficient (each wave reads only its own offl[wave] region).

    // ================= PHASE 2: deform conv (R4 deform body) ================
    const int wo0 = wo_base + wave * 32 + lm;       // mt=0 pixel; mt=1 is +16

    float4v acc[2][4];
#pragma unroll
    for (int mt = 0; mt < 2; mt++)
#pragma unroll
        for (int nt = 0; nt < 4; nt++) acc[mt][nt] = (float4v)0.f;

    float w00[2], w01[2], w10[2], w11[2];
    unsigned e00[2], e01[2], e10[2], e11[2];
    uint4v G[2][4][2];                  // [mt][corner][step], 16B each

    union AFU { short8 v; unsigned u[4]; };

#define COORDS(MT, KY, KX, OY, OX)                                               \
    {                                                                            \
        float sy = (float)(ho - 1 + (KY)) + (OY);                                \
        float sx = (float)(wo0 + (MT) * 16 - 1 + (KX)) + (OX);                   \
        float y0f = floorf(sy), x0f = floorf(sx);                                \
        float dy = sy - y0f, dx = sx - x0f;                                      \
        int y0 = (int)y0f, x0 = (int)x0f;                                        \
        float wy0 = ((unsigned)y0 < 256u) ? (1.f - dy) : 0.f;                    \
        float wy1 = ((unsigned)(y0 + 1) < 256u) ? dy : 0.f;                      \
        float wx0 = ((unsigned)x0 < 256u) ? (1.f - dx) : 0.f;                    \
        float wx1 = ((unsigned)(x0 + 1) < 256u) ? dx : 0.f;                      \
        int yb0 = y0 < 0 ? 0 : (y0 > 255 ? 255 : y0);                            \
        int yb1 = (y0 + 1) < 0 ? 0 : ((y0 + 1) > 255 ? 255 : (y0 + 1));          \
        int xb0 = x0 < 0 ? 0 : (x0 > 255 ? 255 : x0);                            \
        int xb1 = (x0 + 1) < 0 ? 0 : ((x0 + 1) > 255 ? 255 : (x0 + 1));          \
        w00[MT] = wy0 * wx0; w01[MT] = wy0 * wx1;                                \
        w10[MT] = wy1 * wx0; w11[MT] = wy1 * wx1;                                \
        e00[MT] = ((yb0 << 8) + xb0) << 5; e01[MT] = ((yb0 << 8) + xb1) << 5;    \
        e10[MT] = ((yb1 << 8) + xb0) << 5; e11[MT] = ((yb1 << 8) + xb1) << 5;    \
    }

#define ISSUE(MT)                                                                \
    {                                                                            \
        G[MT][0][0] = *(const uint4v*)(fpq + e00[MT]);                           \
        G[MT][0][1] = *(const uint4v*)(fpq + e00[MT] + 16);                      \
        G[MT][1][0] = *(const uint4v*)(fpq + e01[MT]);                           \
        G[MT][1][1] = *(const uint4v*)(fpq + e01[MT] + 16);                      \
        G[MT][2][0] = *(const uint4v*)(fpq + e10[MT]);                           \
        G[MT][2][1] = *(const uint4v*)(fpq + e10[MT] + 16);                      \
        G[MT][3][0] = *(const uint4v*)(fpq + e11[MT]);                           \
        G[MT][3][1] = *(const uint4v*)(fpq + e11[MT] + 16);                      \
    }

#define COMBINE(MT, AF)                                                          \
    _Pragma("unroll")                                                            \
    for (int st = 0; st < 2; st++) {                                             \
        _Pragma("unroll")                                                        \
        for (int j = 0; j < 4; j++) {                                            \
            unsigned u0 = G[MT][0][st][j], u1 = G[MT][1][st][j];                 \
            unsigned u2 = G[MT][2][st][j], u3 = G[MT][3][st][j];                 \
            float g0 = w00[MT] * bf_lo(u0) + w01[MT] * bf_lo(u1)                 \
                     + w10[MT] * bf_lo(u2) + w11[MT] * bf_lo(u3);                \
            float g1 = w00[MT] * bf_hi(u0) + w01[MT] * bf_hi(u1)                 \
                     + w10[MT] * bf_hi(u2) + w11[MT] * bf_hi(u3);                \
            AF[st].u[j] = pack_bf16x2(g0, g1);                                   \
        }                                                                        \
    }

#define MFMA_MT(MT, AF)                                                          \
    _Pragma("unroll")                                                            \
    for (int nt = 0; nt < 4; nt++)                                               \
        acc[MT][nt] = __builtin_amdgcn_mfma_f32_16x16x32_bf16(                   \
            AF[0].v, bfr[0][nt], acc[MT][nt], 0, 0, 0);                          \
    _Pragma("unroll")                                                            \
    for (int nt = 0; nt < 4; nt++)                                               \
        acc[MT][nt] = __builtin_amdgcn_mfma_f32_16x16x32_bf16(                   \
            AF[1].v, bfr[1][nt], acc[MT][nt], 0, 0, 0);

    // Prologue: gather tap 0 for both mt (offsets from LDS)
    {
        float oy0 = offw[0 * 33 + lm],      ox0 = offw[1 * 33 + lm];
        float oy1 = offw[0 * 33 + lm + 16], ox1 = offw[1 * 33 + lm + 16];
        COORDS(0, 0, 0, oy0, ox0);
        ISSUE(0);
        COORDS(1, 0, 0, oy1, ox1);
        ISSUE(1);
    }

    for (int tap = 0; tap < 9; ++tap) {
        float ny0 = 0.f, nx0 = 0.f, ny1 = 0.f, nx1 = 0.f;
        if (tap < 8) {                                  // next-tap offsets, early
            const float* p = offw + (2 * tap + 2) * 33;
            ny0 = p[lm];      ny1 = p[lm + 16];
            nx0 = p[33 + lm]; nx1 = p[33 + lm + 16];
        }
        short8 bfr[2][4];                               // B-frags, both steps
        {
            const unsigned short* wp = wtf + (size_t)tap * 4096 + lane * 8;
#pragma unroll
            for (int nt = 0; nt < 4; nt++) {
                bfr[0][nt] = *(const short8*)(wp + (nt << 9));
                bfr[1][nt] = *(const short8*)(wp + 2048 + (nt << 9));
            }
        }
        const int tn  = tap + 1;
        const int nky = (int)((unsigned)tn / 3u);
        const int nkx = tn - 3 * nky;

        AFU af[2];
        COMBINE(0, af);                                 // G0 issued last tap
        MFMA_MT(0, af);
        if (tap < 8) { COORDS(0, nky, nkx, ny0, nx0); ISSUE(0); }
        COMBINE(1, af);                                 // G1 issued last tap
        MFMA_MT(1, af);
        if (tap < 8) { COORDS(1, nky, nkx, ny1, nx1); ISSUE(1); }
    }

#pragma unroll
    for (int nt = 0; nt < 4; nt++) {
        int oc = nt * 16 + lm;
        float bv = db[oc];
        float* op = out + (((size_t)(b * 64 + oc)) << 16) + (ho << 8)
                  + wo_base + wave * 32 + quad * 4;
#pragma unroll
        for (int mt = 0; mt < 2; mt++) {
            float4 v = {acc[mt][nt][0] + bv, acc[mt][nt][1] + bv,
                        acc[mt][nt][2] + bv, acc[mt][nt][3] + bv};
            *(float4*)(op + mt * 16) = v;
        }
    }
#undef COORDS
#undef ISSUE
#undef COMBINE
#undef MFMA_MT
}

// ---------------------------------------------------------------------------
extern "C" void kernel_launch(void* const* d_in, const int* in_sizes, int n_in,
                              void* d_out, int out_size, void* d_ws, size_t ws_size,
                              hipStream_t stream) {
    const float* x  = (const float*)d_in[0];
    const float* cw = (const float*)d_in[1];
    const float* cb = (const float*)d_in[2];
    const float* ow = (const float*)d_in[3];
    const float* ob = (const float*)d_in[4];
    const float* dw = (const float*)d_in[5];
    const float* db = (const float*)d_in[6];
    float* out = (float*)d_out;

    unsigned short* featp = (unsigned short*)d_ws;       // 33.5 MB bf16 NHWC
    float* offsb = (float*)(featp + FEAT_N);             // dead region (fusion) — reuse
    unsigned short* wt1f = (unsigned short*)offsb;       // 4 KB conv1 B-frags
    unsigned short* wtf  = (unsigned short*)(offsb + OFFS_N);  // 72 KB
    unsigned short* wt2f = wtf + WTF_N;                  // 36 KB

    prep_weights<<<224, 256, 0, stream>>>(dw, ow, cw, wtf, wt2f, wt1f);
    conv1_kernel<<<1024, 256, 0, stream>>>(x, wt1f, cb, featp);
    fused_kernel<<<2048, 256, 0, stream>>>(featp, wt2f, ob, wtf, db, out);
}

// Round 9
// 276.836 us; speedup vs baseline: 1.5150x; 1.0059x over previous
//
#include <hip/hip_runtime.h>
#include <hip/hip_fp16.h>

// Problem constants: B=4, H=W=256, C=64, OC=64, K=3, PAD=1
#define FEAT_N (4*64*256*256)
#define OFFS_N (4*18*256*256)
#define WTF_N  (576*64)            // deform weights, fp16, MFMA-B-fragment order
#define WT2F_N (576*32)            // offset-conv weights, fp16 frags, N padded to 32
#define WT1F_N (4*64*8)            // conv1 weights, fp16 B-frags, K=32 (27 real), N=64

typedef __attribute__((ext_vector_type(8))) _Float16 half8;
typedef __attribute__((ext_vector_type(4))) float float4v;
typedef __attribute__((ext_vector_type(4))) unsigned uint4v;

__device__ __forceinline__ unsigned short f2h(float f) {
    union { __half h; unsigned short u; } c; c.h = __float2half_rn(f); return c.u;
}
__device__ __forceinline__ __half2 u2h2(unsigned u) {
    union { unsigned u; __half2 h; } c; c.u = u; return c.h;
}
__device__ __forceinline__ unsigned h22u(__half2 h) {
    union { __half2 h; unsigned u; } c; c.h = h; return c.u;
}

// ---------------------------------------------------------------------------
// Weight prep (R8 structure, fp16): wtf (deform B-frags), wt2f (offset-conv
// B-frags, oc>=18 zero), wt1f (conv1 B-frags, K padded to 32).
// ---------------------------------------------------------------------------
__global__ __launch_bounds__(256) void prep_weights(const float* __restrict__ dw,
                                                    const float* __restrict__ ow,
                                                    const float* __restrict__ cw,
                                                    unsigned short* __restrict__ wtf,
                                                    unsigned short* __restrict__ wt2f,
                                                    unsigned short* __restrict__ wt1f) {
    int idx = blockIdx.x * 256 + threadIdx.x;
    if (idx < WTF_N) {
        int j    = idx & 7;
        int lane = (idx >> 3) & 63;
        int nt   = (idx >> 9) & 3;
        int ks   = idx >> 11;
        int k    = ks * 32 + ((lane >> 4) << 3) + j;
        int tap  = k >> 6;
        int ic   = k & 63;
        int n    = nt * 16 + (lane & 15);
        wtf[idx] = f2h(dw[n * 576 + ic * 9 + tap]);
    }
    int i2 = idx - WTF_N;
    if (i2 >= 0 && i2 < WT2F_N) {
        int j    = i2 & 7;
        int lane = (i2 >> 3) & 63;
        int nt   = (i2 >> 9) & 1;
        int ks   = i2 >> 10;
        int k    = ks * 32 + ((lane >> 4) << 3) + j;
        int tap  = k >> 6;
        int ic   = k & 63;
        int n    = nt * 16 + (lane & 15);
        wt2f[i2] = (n < 18) ? f2h(ow[n * 576 + ic * 9 + tap]) : (unsigned short)0;
    }
    int i3 = idx - WTF_N - WT2F_N;
    if (i3 >= 0 && i3 < WT1F_N) {
        int j    = i3 & 7;
        int lane = (i3 >> 3) & 63;
        int nt   = (i3 >> 9) & 3;
        int n    = nt * 16 + (lane & 15);
        int k    = ((lane >> 4) << 3) + j;
        wt1f[i3] = (k < 27) ? f2h(cw[n * 27 + k]) : (unsigned short)0;
    }
}

// ---------------------------------------------------------------------------
// conv1 (R8 structure, fp16): MFMA im2col GEMM, M=256 px, N=64 oc, K=32.
// x halo staged in LDS as fp16; featp output NHWC fp16 (ushort idx =
// pixel_lin*64 + oc), identical indexing to R8.
// ---------------------------------------------------------------------------
__global__ __launch_bounds__(256) void conv1_kernel(const float* __restrict__ x,
                                                    const unsigned short* __restrict__ wt1f,
                                                    const float* __restrict__ cb,
                                                    unsigned short* __restrict__ featp) {
    __shared__ unsigned short xs[10 * 264];   // rows 0..8 = (ic*3+ti), row 9 = zeros
    const int tid  = threadIdx.x;
    const int lane = tid & 63;
    const int wave = tid >> 6;
    const int lm   = lane & 15;
    const int quad = lane >> 4;

    const int bx = blockIdx.x;
    const int b  = bx >> 8;
    const int h  = bx & 255;

    // ---- stage x halo rows (fp16, zero borders) ----
#pragma unroll
    for (int r = 0; r < 9; r++) {
        const int ic = r / 3, ti = r % 3;                 // static
        const int srow = h - 1 + ti;
        const bool rok = (unsigned)srow < 256u;
        const float* xrow = x + ((b * 3 + ic) << 16) + (srow << 8);
        {
            const int c = tid;                            // c=0..255
            float v = (rok && (unsigned)(c - 1) < 256u) ? xrow[c - 1] : 0.f;
            xs[r * 264 + c] = f2h(v);
        }
        if (tid < 2) {
            const int c = tid + 256;                      // c=256,257
            float v = (rok && (unsigned)(c - 1) < 256u) ? xrow[c - 1] : 0.f;
            xs[r * 264 + c] = f2h(v);
        }
    }
    xs[9 * 264 + tid] = 0;
    if (tid < 8) xs[9 * 264 + 256 + tid] = 0;
    __syncthreads();

    // ---- per-lane A-offsets: k = quad*8+j -> xs row k/3, col-offset k%3 ----
    int off[8];
#pragma unroll
    for (int j = 0; j < 8; j++) {
        const int k = quad * 8 + j;
        const int row = (k < 27) ? (k / 3) : 9;
        const int tj  = (k < 27) ? (k - row * 3) : 0;
        off[j] = row * 264 + tj;
    }

    // ---- B-frags + bias, loaded once ----
    half8 bw[4];
#pragma unroll
    for (int nt = 0; nt < 4; nt++)
        bw[nt] = *(const half8*)(wt1f + nt * 512 + lane * 8);
    float bias[4];
#pragma unroll
    for (int nt = 0; nt < 4; nt++) bias[nt] = cb[nt * 16 + lm];

    unsigned short* fpx = featp + ((((size_t)b << 16) + (h << 8)) << 6);  // +px*64+oc

#pragma unroll
    for (int mt = 0; mt < 4; mt++) {
        const int px = wave * 64 + mt * 16 + lm;          // A-row pixel for this lane
        union { half8 v; unsigned u[4]; } af;
#pragma unroll
        for (int jj = 0; jj < 4; jj++) {
            unsigned lo = xs[off[2 * jj]     + px];
            unsigned hi = xs[off[2 * jj + 1] + px];
            af.u[jj] = lo | (hi << 16);
        }
        float4v d[4];
#pragma unroll
        for (int nt = 0; nt < 4; nt++)
            d[nt] = __builtin_amdgcn_mfma_f32_16x16x32_f16(af.v, bw[nt], (float4v)0.f, 0, 0, 0);

        const int pxs = wave * 64 + mt * 16 + quad * 4;   // D-row pixel base
#pragma unroll
        for (int r = 0; r < 4; r++) {
            unsigned short* sp = fpx + (size_t)(pxs + r) * 64 + lm;
#pragma unroll
            for (int nt = 0; nt < 4; nt++)
                sp[nt * 16] = f2h(d[nt][r] + bias[nt]);
        }
    }
}

// ---------------------------------------------------------------------------
// FUSED conv2 + deform (R7/R8 structure, fp16 + packed-fp16 COMBINE).
// Phase 1 = offset conv via f16 MFMA -> per-wave LDS. Phase 2 = deform with
// register-pipelined gathers; bilinear combine is 4 packed-fp16 ops per
// dword (v_pk_mul/fma_f16) feeding the f16 MFMA A-operand directly.
// ---------------------------------------------------------------------------
__global__ __launch_bounds__(256, 3) void fused_kernel(const unsigned short* __restrict__ featp,
                                                       const unsigned short* __restrict__ wt2f,
                                                       const float* __restrict__ ob,
                                                       const unsigned short* __restrict__ wtf,
                                                       const float* __restrict__ db,
                                                       float* __restrict__ out) {
    __shared__ float offl[4][18 * 33];   // [wave][oc*33 + pxw], 9504 B

    const int tid  = threadIdx.x;
    const int lane = tid & 63;
    const int wave = tid >> 6;
    const int lm   = lane & 15;
    const int quad = lane >> 4;

    const int bx = blockIdx.x;
    const int strip = ((bx & 7) << 8) | (bx >> 3);
    const int wo_base = (strip & 1) << 7;
    const int ho = (strip >> 1) & 255;
    const int b  = strip >> 9;

    const unsigned* fpq = (const unsigned*)featp + ((size_t)b << 21) + quad * 4;
    const int colb = wo_base + wave * 32 + lm;
    float* offw = &offl[wave][0];

    // ================= PHASE 1: offset conv =================
    {
        float4v acc[2][2];
#pragma unroll
        for (int mt = 0; mt < 2; mt++)
#pragma unroll
            for (int nt = 0; nt < 2; nt++) acc[mt][nt] = (float4v)0.f;

        uint4v A[2][2];

#define C2LOAD(KY, KX, DST)                                                      \
    {                                                                            \
        const int row = ho - 1 + (KY);                                           \
        const bool rok = (unsigned)row < 256u;                                   \
        _Pragma("unroll")                                                        \
        for (int mt = 0; mt < 2; mt++) {                                         \
            const int col = colb + mt * 16 + (KX) - 1;                           \
            DST[mt][0] = (uint4v)0;                                              \
            DST[mt][1] = (uint4v)0;                                              \
            if (rok && (unsigned)col < 256u) {                                   \
                const unsigned* p = fpq + (((row << 8) + col) << 5);             \
                DST[mt][0] = *(const uint4v*)p;                                  \
                DST[mt][1] = *(const uint4v*)(p + 16);                           \
            }                                                                    \
        }                                                                        \
    }

        C2LOAD(0, 0, A);

#pragma unroll
        for (int tap = 0; tap < 9; tap++) {
            half8 bfr[2][2];
            const unsigned short* wp = wt2f + (size_t)(tap * 2) * 1024 + lane * 8;
#pragma unroll
            for (int st = 0; st < 2; st++) {
                bfr[st][0] = *(const half8*)(wp + st * 1024);
                bfr[st][1] = *(const half8*)(wp + st * 1024 + 512);
            }
            uint4v N[2][2];
            if (tap < 8) {
                const int tn  = tap + 1;
                const int tky = tn / 3;
                const int tkx = tn - 3 * tky;
                C2LOAD(tky, tkx, N);
            }
#pragma unroll
            for (int mt = 0; mt < 2; mt++) {
                union { half8 v; uint4v u; } f0, f1;
                f0.u = A[mt][0]; f1.u = A[mt][1];
                acc[mt][0] = __builtin_amdgcn_mfma_f32_16x16x32_f16(f0.v, bfr[0][0], acc[mt][0], 0, 0, 0);
                acc[mt][1] = __builtin_amdgcn_mfma_f32_16x16x32_f16(f0.v, bfr[0][1], acc[mt][1], 0, 0, 0);
                acc[mt][0] = __builtin_amdgcn_mfma_f32_16x16x32_f16(f1.v, bfr[1][0], acc[mt][0], 0, 0, 0);
                acc[mt][1] = __builtin_amdgcn_mfma_f32_16x16x32_f16(f1.v, bfr[1][1], acc[mt][1], 0, 0, 0);
            }
            if (tap < 8) {
#pragma unroll
                for (int mt = 0; mt < 2; mt++) {
                    A[mt][0] = N[mt][0];
                    A[mt][1] = N[mt][1];
                }
            }
        }
#undef C2LOAD

        // Store offsets to per-wave LDS. pxw = mt*16+quad*4+r.
#pragma unroll
        for (int nt = 0; nt < 2; nt++) {
            int oc = nt * 16 + lm;
            if (oc < 18) {
                float bv = ob[oc];
#pragma unroll
                for (int mt = 0; mt < 2; mt++) {
#pragma unroll
                    for (int r = 0; r < 4; r++)
                        offw[oc * 33 + mt * 16 + quad * 4 + r] = acc[mt][nt][r] + bv;
                }
            }
        }
    }
    // Intra-wave producer/consumer: each wave reads only its own offl[wave].

    // ================= PHASE 2: deform conv =================
    const int wo0 = wo_base + wave * 32 + lm;       // mt=0 pixel; mt=1 is +16

    float4v acc[2][4];
#pragma unroll
    for (int mt = 0; mt < 2; mt++)
#pragma unroll
        for (int nt = 0; nt < 4; nt++) acc[mt][nt] = (float4v)0.f;

    __half2 wh00[2], wh01[2], wh10[2], wh11[2];
    unsigned e00[2], e01[2], e10[2], e11[2];
    uint4v G[2][4][2];                  // [mt][corner][step], 16B each

    union AFU { half8 v; unsigned u[4]; };

#define COORDS(MT, KY, KX, OY, OX)                                               \
    {                                                                            \
        float sy = (float)(ho - 1 + (KY)) + (OY);                                \
        float sx = (float)(wo0 + (MT) * 16 - 1 + (KX)) + (OX);                   \
        float y0f = floorf(sy), x0f = floorf(sx);                                \
        float dy = sy - y0f, dx = sx - x0f;                                      \
        int y0 = (int)y0f, x0 = (int)x0f;                                        \
        float wy0 = ((unsigned)y0 < 256u) ? (1.f - dy) : 0.f;                    \
        float wy1 = ((unsigned)(y0 + 1) < 256u) ? dy : 0.f;                      \
        float wx0 = ((unsigned)x0 < 256u) ? (1.f - dx) : 0.f;                    \
        float wx1 = ((unsigned)(x0 + 1) < 256u) ? dx : 0.f;                      \
        int yb0 = y0 < 0 ? 0 : (y0 > 255 ? 255 : y0);                            \
        int yb1 = (y0 + 1) < 0 ? 0 : ((y0 + 1) > 255 ? 255 : (y0 + 1));          \
        int xb0 = x0 < 0 ? 0 : (x0 > 255 ? 255 : x0);                            \
        int xb1 = (x0 + 1) < 0 ? 0 : ((x0 + 1) > 255 ? 255 : (x0 + 1));          \
        wh00[MT] = __float2half2_rn(wy0 * wx0);                                  \
        wh01[MT] = __float2half2_rn(wy0 * wx1);                                  \
        wh10[MT] = __float2half2_rn(wy1 * wx0);                                  \
        wh11[MT] = __float2half2_rn(wy1 * wx1);                                  \
        e00[MT] = ((yb0 << 8) + xb0) << 5; e01[MT] = ((yb0 << 8) + xb1) << 5;    \
        e10[MT] = ((yb1 << 8) + xb0) << 5; e11[MT] = ((yb1 << 8) + xb1) << 5;    \
    }

#define ISSUE(MT)                                                                \
    {                                                                            \
        G[MT][0][0] = *(const uint4v*)(fpq + e00[MT]);                           \
        G[MT][0][1] = *(const uint4v*)(fpq + e00[MT] + 16);                      \
        G[MT][1][0] = *(const uint4v*)(fpq + e01[MT]);                           \
        G[MT][1][1] = *(const uint4v*)(fpq + e01[MT] + 16);                      \
        G[MT][2][0] = *(const uint4v*)(fpq + e10[MT]);                           \
        G[MT][2][1] = *(const uint4v*)(fpq + e10[MT] + 16);                      \
        G[MT][3][0] = *(const uint4v*)(fpq + e11[MT]);                           \
        G[MT][3][1] = *(const uint4v*)(fpq + e11[MT] + 16);                      \
    }

#define COMBINE(MT, AF)                                                          \
    _Pragma("unroll")                                                            \
    for (int st = 0; st < 2; st++) {                                             \
        _Pragma("unroll")                                                        \
        for (int j = 0; j < 4; j++) {                                            \
            __half2 s = __hmul2(wh00[MT], u2h2(G[MT][0][st][j]));                \
            s = __hfma2(wh01[MT], u2h2(G[MT][1][st][j]), s);                     \
            s = __hfma2(wh10[MT], u2h2(G[MT][2][st][j]), s);                     \
            s = __hfma2(wh11[MT], u2h2(G[MT][3][st][j]), s);                     \
            AF[st].u[j] = h22u(s);                                               \
        }                                                                        \
    }

#define MFMA_MT(MT, AF)                                                          \
    _Pragma("unroll")                                                            \
    for (int nt = 0; nt < 4; nt++)                                               \
        acc[MT][nt] = __builtin_amdgcn_mfma_f32_16x16x32_f16(                    \
            AF[0].v, bfr[0][nt], acc[MT][nt], 0, 0, 0);                          \
    _Pragma("unroll")                                                            \
    for (int nt = 0; nt < 4; nt++)                                               \
        acc[MT][nt] = __builtin_amdgcn_mfma_f32_16x16x32_f16(                    \
            AF[1].v, bfr[1][nt], acc[MT][nt], 0, 0, 0);

    // Prologue: gather tap 0 for both mt (offsets from LDS)
    {
        float oy0 = offw[0 * 33 + lm],      ox0 = offw[1 * 33 + lm];
        float oy1 = offw[0 * 33 + lm + 16], ox1 = offw[1 * 33 + lm + 16];
        COORDS(0, 0, 0, oy0, ox0);
        ISSUE(0);
        COORDS(1, 0, 0, oy1, ox1);
        ISSUE(1);
    }

    for (int tap = 0; tap < 9; ++tap) {
        float ny0 = 0.f, nx0 = 0.f, ny1 = 0.f, nx1 = 0.f;
        if (tap < 8) {                                  // next-tap offsets, early
            const float* p = offw + (2 * tap + 2) * 33;
            ny0 = p[lm];      ny1 = p[lm + 16];
            nx0 = p[33 + lm]; nx1 = p[33 + lm + 16];
        }
        half8 bfr[2][4];                                // B-frags, both steps
        {
            const unsigned short* wp = wtf + (size_t)tap * 4096 + lane * 8;
#pragma unroll
            for (int nt = 0; nt < 4; nt++) {
                bfr[0][nt] = *(const half8*)(wp + (nt << 9));
                bfr[1][nt] = *(const half8*)(wp + 2048 + (nt << 9));
            }
        }
        const int tn  = tap + 1;
        const int nky = (int)((unsigned)tn / 3u);
        const int nkx = tn - 3 * nky;

        AFU af[2];
        COMBINE(0, af);                                 // G0 issued last tap
        MFMA_MT(0, af);
        if (tap < 8) { COORDS(0, nky, nkx, ny0, nx0); ISSUE(0); }
        COMBINE(1, af);                                 // G1 issued last tap
        MFMA_MT(1, af);
        if (tap < 8) { COORDS(1, nky, nkx, ny1, nx1); ISSUE(1); }
    }

#pragma unroll
    for (int nt = 0; nt < 4; nt++) {
        int oc = nt * 16 + lm;
        float bv = db[oc];
        float* op = out + (((size_t)(b * 64 + oc)) << 16) + (ho << 8)
                  + wo_base + wave * 32 + quad * 4;
#pragma unroll
        for (int mt = 0; mt < 2; mt++) {
            float4 v = {acc[mt][nt][0] + bv, acc[mt][nt][1] + bv,
                        acc[mt][nt][2] + bv, acc[mt][nt][3] + bv};
            *(float4*)(op + mt * 16) = v;
        }
    }
#undef COORDS
#undef ISSUE
#undef COMBINE
#undef MFMA_MT
}

// ---------------------------------------------------------------------------
extern "C" void kernel_launch(void* const* d_in, const int* in_sizes, int n_in,
                              void* d_out, int out_size, void* d_ws, size_t ws_size,
                              hipStream_t stream) {
    const float* x  = (const float*)d_in[0];
    const float* cw = (const float*)d_in[1];
    const float* cb = (const float*)d_in[2];
    const float* ow = (const float*)d_in[3];
    const float* ob = (const float*)d_in[4];
    const float* dw = (const float*)d_in[5];
    const float* db = (const float*)d_in[6];
    float* out = (float*)d_out;

    unsigned short* featp = (unsigned short*)d_ws;       // 33.5 MB fp16 NHWC
    float* offsb = (float*)(featp + FEAT_N);             // dead region — reuse
    unsigned short* wt1f = (unsigned short*)offsb;       // 4 KB conv1 B-frags
    unsigned short* wtf  = (unsigned short*)(offsb + OFFS_N);  // 72 KB
    unsigned short* wt2f = wtf + WTF_N;                  // 36 KB

    prep_weights<<<224, 256, 0, stream>>>(dw, ow, cw, wtf, wt2f, wt1f);
    conv1_kernel<<<1024, 256, 0, stream>>>(x, wt1f, cb, featp);
    fused_kernel<<<2048, 256, 0, stream>>>(featp, wt2f, ob, wtf, db, out);
}